// Round 6
// baseline (409.854 us; speedup 1.0000x reference)
//
#include <hip/hip_runtime.h>

typedef __bf16 bf16;
typedef __bf16 bf16x2 __attribute__((ext_vector_type(2)));
typedef __bf16 bf16x4 __attribute__((ext_vector_type(4)));
typedef __bf16 bf16x8 __attribute__((ext_vector_type(8)));
typedef float f32x4 __attribute__((ext_vector_type(4)));
typedef float f32x16 __attribute__((ext_vector_type(16)));

#define MFMA_BF16(a, b, c) __builtin_amdgcn_mfma_f32_16x16x32_bf16(a, b, c, 0, 0, 0)
#define MFMA32(a, b, c)    __builtin_amdgcn_mfma_f32_32x32x16_bf16(a, b, c, 0, 0, 0)

__device__ __forceinline__ void async16(const void* g, void* l) {
    __builtin_amdgcn_global_load_lds(
        (const __attribute__((address_space(1))) void*)g,
        (__attribute__((address_space(3))) void*)l,
        16, 0, 0);
}

__device__ __forceinline__ unsigned pack2(float a, float b) {
    bf16x2 t; t[0] = (bf16)a; t[1] = (bf16)b;
    return __builtin_bit_cast(unsigned, t);
}

// ---------------- fp32 -> bf16 convert, 8 elems/thread ----------------
__global__ void cvt8(const float* __restrict__ in, bf16* __restrict__ out, int n) {
    int i = (blockIdx.x * 256 + threadIdx.x) * 8;
    if (i >= n) return;
    float4 a = *(const float4*)(in + i);
    float4 b = *(const float4*)(in + i + 4);
    bf16x8 o;
    o[0] = (bf16)a.x; o[1] = (bf16)a.y; o[2] = (bf16)a.z; o[3] = (bf16)a.w;
    o[4] = (bf16)b.x; o[5] = (bf16)b.y; o[6] = (bf16)b.z; o[7] = (bf16)b.w;
    *(bf16x8*)(out + i) = o;
}

// ---------------- RoPE tables + key-mask bias (pre-scaled by 1/ln2) ----------------
__global__ void tables_k(const int* __restrict__ am, float* __restrict__ cosT,
                         float* __restrict__ sinT, float* __restrict__ mbias) {
    int i = blockIdx.x * 256 + threadIdx.x;   // 0 .. 2048*128-1
    int s = i >> 7, d = i & 127, fi = d & 63;
    float inv = exp2f(-(float)fi * (13.287712379549449f / 64.0f));
    float ang = (float)s * inv;
    cosT[i] = cosf(ang);
    sinT[i] = sinf(ang);
    if (i < 2 * 2048) mbias[i] = (am[i] == 0) ? -1.4427e30f : 0.0f;  // /ln2 domain
}

// ---------------- GEMM: C[M,N] = A[M,K] @ Bt[N,K]^T + bias ----------------
// (unchanged — at the m97-structure plateau, ~830 TF)
template <int EPI>
__global__ void __launch_bounds__(256, 2)
gemm_bt(const bf16* __restrict__ A, const bf16* __restrict__ Bt,
        const float* __restrict__ bias, float* __restrict__ Cf,
        bf16* __restrict__ qb, bf16* __restrict__ kb, bf16* __restrict__ vtb,
        const float* __restrict__ cosT, const float* __restrict__ sinT,
        int M, int N, int K, int bn0) {
    __shared__ __align__(16) bf16 sA[128 * 64];
    __shared__ __align__(16) bf16 sB[128 * 64];
    const int tid  = threadIdx.x;
    const int lane = tid & 63;
    const int quad = lane >> 4, l15 = lane & 15;
    const int wid = tid >> 6, wm = wid >> 1, wn = wid & 1;
    const int bm = blockIdx.x, bn = blockIdx.y + bn0;

    f32x4 acc[4][4];
#pragma unroll
    for (int i = 0; i < 4; i++)
#pragma unroll
        for (int j = 0; j < 4; j++)
#pragma unroll
            for (int c = 0; c < 4; c++) acc[i][j][c] = 0.0f;

    const int r0 = tid >> 3, x0 = tid & 7;
    const int g0 = x0 ^ (r0 & 7);
    const bf16* pa = A  + (size_t)(bm * 128 + r0) * K + g0 * 8;
    const bf16* pb = Bt + (size_t)(bn * 128 + r0) * K + g0 * 8;
    bf16* la = sA + tid * 8;
    bf16* lb = sB + tid * 8;
    const size_t gstep = (size_t)32 * K;

    for (int k0 = 0; k0 < K; k0 += 64) {
#pragma unroll
        for (int i = 0; i < 4; i++) {
            async16(pa + i * gstep, la + i * 2048);
            async16(pb + i * gstep, lb + i * 2048);
        }
        pa += 64; pb += 64;
        __syncthreads();
#pragma unroll
        for (int ks = 0; ks < 2; ks++) {
            bf16x8 af[4], bfr[4];
#pragma unroll
            for (int i = 0; i < 4; i++) {
                int r = wm * 64 + i * 16 + l15;
                int x = (ks * 4 + quad) ^ (r & 7);
                af[i] = *(const bf16x8*)(sA + r * 64 + x * 8);
            }
#pragma unroll
            for (int i = 0; i < 4; i++) {
                int r = wn * 64 + i * 16 + l15;
                int x = (ks * 4 + quad) ^ (r & 7);
                bfr[i] = *(const bf16x8*)(sB + r * 64 + x * 8);
            }
#pragma unroll
            for (int mi = 0; mi < 4; mi++)
#pragma unroll
                for (int ni = 0; ni < 4; ni++)
                    acc[mi][ni] = MFMA_BF16(af[mi], bfr[ni], acc[mi][ni]);
        }
        __syncthreads();
    }

    if (EPI == 0) {
#pragma unroll
        for (int mi = 0; mi < 4; mi++)
#pragma unroll
            for (int ni = 0; ni < 4; ni++) {
                int row0 = bm * 128 + wm * 64 + mi * 16 + quad * 4;
                int col  = bn * 128 + wn * 64 + ni * 16 + l15;
                float bv = bias[col];
#pragma unroll
                for (int r = 0; r < 4; r++)
                    Cf[(size_t)(row0 + r) * N + col] = acc[mi][ni][r] + bv;
            }
    } else {
#pragma unroll
        for (int mi = 0; mi < 4; mi++)
#pragma unroll
            for (int ni = 0; ni < 4; ni++) {
                int col   = bn * 128 + wn * 64 + ni * 16 + l15;
                int which = col >> 11;
                int hcol  = col & 2047;
                int h = hcol >> 7, d = hcol & 127;
                float bv = bias[col];
#pragma unroll
                for (int r = 0; r < 4; r++) {
                    int row = bm * 128 + wm * 64 + mi * 16 + quad * 4 + r;
                    int b = row >> 11, s = row & 2047;
                    float v  = acc[mi][ni][r] + bv;
                    float vp = __shfl_xor(v, 1, 64);   // partner column d^1
                    float ov = v;
                    if (which < 2) {
                        float c  = cosT[(s << 7) + d];
                        float sn = sinT[(s << 7) + d];
                        ov = v * c + ((d & 1) ? vp : -vp) * sn;
                    }
                    // q pre-scale: 1/sqrt(128)/ln2 (exp2-domain softmax)
                    if (which == 0) ov *= 0.12751743f;
                    size_t bh = (size_t)(b * 16 + h);
                    if (which == 0)      qb[(bh * 2048 + s) * 128 + d] = (bf16)ov;
                    else if (which == 1) kb[(bh * 2048 + s) * 128 + d] = (bf16)ov;
                    else                 vtb[(bh * 128 + d) * 2048 + s] = (bf16)ov;
                }
            }
    }
}

// ---------------- Flash attention v5: 32x32x16, S^T/O^T, dbuf, no sP ----------------
// BM=128 (4 waves x 32 q), BN=64, grid 512 1-D: blocks 0..255 take qt 15..8
// (heavy), 256..511 take qt 0..7 — rounds of 256 land on the same CU sequence,
// pairing heavy+light per CU. P never touches LDS: PV B-fragments are built
// from the S^T C-layout registers via one cross-half dword exchange per step.
// Swizzles fold high row bits so every 8-lane group covers all 32 banks.
__global__ void __launch_bounds__(256, 2)
fattn(const bf16* __restrict__ Q, const bf16* __restrict__ Kg,
      const bf16* __restrict__ Vt, const float* __restrict__ mbias,
      bf16* __restrict__ O) {
    __shared__ __align__(16) bf16 sK[2][64 * 128];   // [buf][key][d]
    __shared__ __align__(16) bf16 sV[2][128 * 64];   // [buf][d][key]
    const int tid = threadIdx.x, lane = tid & 63, w = tid >> 6;
    const int l31 = lane & 31, half = lane >> 5;
    const int id = (int)blockIdx.x;
    const int round = id >> 8, u = id & 255;
    const int bh = u & 31, j8 = u >> 5;
    const int qt = round ? j8 : 15 - j8;
    const int b = bh >> 4, hh = bh & 15;
    const int myq = qt * 128 + w * 32 + l31;
    const int qmin = qt * 128 + w * 32;

    const bf16* Qb  = Q  + (size_t)bh * 2048 * 128;
    const bf16* Kbh = Kg + (size_t)bh * 2048 * 128;
    const bf16* Vbh = Vt + (size_t)bh * 128 * 2048;
    const float* mbb = mbias + b * 2048;

    // per-lane read swizzles
    const int swk = (l31 & 15) ^ (l31 >> 4);          // sK: 16 chunks/row
    const int swv = (l31 & 7) ^ ((l31 >> 3) & 3);     // sV: 8 chunks/row

    // resident Q fragments: B-operand, n=query(l31), k = kq*16 + half*8 + j
    bf16x8 qf[8];
#pragma unroll
    for (int kq = 0; kq < 8; kq++)
        qf[kq] = *(const bf16x8*)(Qb + (size_t)myq * 128 + kq * 16 + half * 8);

    f32x16 oacc[4];
#pragma unroll
    for (int dt = 0; dt < 4; dt++)
#pragma unroll
        for (int c = 0; c < 16; c++) oacc[dt][c] = 0.0f;
    float m_s = -3e38f, l_s = 0.0f;   // per-half partial l

    // staging indices (source chunk xor'd so LDS pos p holds global chunk p^swz(row))
    const int rk = tid >> 4, xk = tid & 15, gkb = xk ^ rk;            // ^ (i&1) per i
    const int rv = tid >> 3, xv = tid & 7;
    const int gv = xv ^ (rv & 7) ^ ((rv >> 3) & 3);
    const int nkt = 2 * qt + 2;

    // stage tile 0 into buffer 0
#pragma unroll
    for (int i = 0; i < 4; i++) {
        async16(Kbh + (size_t)(rk + i * 16) * 128 + (gkb ^ (i & 1)) * 8,
                &sK[0][(i * 256 + tid) * 8]);
        async16(Vbh + (size_t)(rv + i * 32) * 2048 + gv * 8,
                &sV[0][(i * 256 + tid) * 8]);
    }
    __syncthreads();

    for (int kt = 0; kt < nkt; kt++) {
        const int kb0 = kt * 64;
        const int buf = kt & 1;
        if (kt + 1 < nkt) {
            const int nb0 = kb0 + 64;
#pragma unroll
            for (int i = 0; i < 4; i++) {
                async16(Kbh + (size_t)(nb0 + rk + i * 16) * 128 + (gkb ^ (i & 1)) * 8,
                        &sK[buf ^ 1][(i * 256 + tid) * 8]);
                async16(Vbh + (size_t)(rv + i * 32) * 2048 + nb0 + gv * 8,
                        &sV[buf ^ 1][(i * 256 + tid) * 8]);
            }
        }
        const bf16* sKb = sK[buf];
        const bf16* sVb = sV[buf];

        // S^T: rows = keys (2 tiles of 32), col = query
        f32x16 sacc[2];
#pragma unroll
        for (int t = 0; t < 2; t++)
#pragma unroll
            for (int c = 0; c < 16; c++) sacc[t][c] = 0.0f;
#pragma unroll
        for (int kq = 0; kq < 8; kq++) {
#pragma unroll
            for (int t = 0; t < 2; t++) {
                int row = t * 32 + l31;
                int x = (kq * 2 + half) ^ swk;
                bf16x8 kf = *(const bf16x8*)(sKb + row * 128 + x * 8);
                sacc[t] = MFMA32(kf, qf[kq], sacc[t]);
            }
        }

        // mask in-place in sacc (exp2 domain; scale folded into q, mbias pre-scaled)
        float mx = -3e38f;
        if (kb0 + 63 < qmin) {          // interior tile: no causal test needed
#pragma unroll
            for (int t = 0; t < 2; t++)
#pragma unroll
                for (int g = 0; g < 4; g++) {
                    float4 mb4 = *(const float4*)(mbb + kb0 + t * 32 + 8 * g + 4 * half);
#pragma unroll
                    for (int r2 = 0; r2 < 4; r2++) {
                        float v = sacc[t][g * 4 + r2] + ((const float*)&mb4)[r2];
                        sacc[t][g * 4 + r2] = v;
                        mx = fmaxf(mx, v);
                    }
                }
        } else {
#pragma unroll
            for (int t = 0; t < 2; t++)
#pragma unroll
                for (int g = 0; g < 4; g++) {
                    float4 mb4 = *(const float4*)(mbb + kb0 + t * 32 + 8 * g + 4 * half);
#pragma unroll
                    for (int r2 = 0; r2 < 4; r2++) {
                        int sk = kb0 + t * 32 + 8 * g + 4 * half + r2;
                        float v = sacc[t][g * 4 + r2] + ((const float*)&mb4)[r2];
                        v = (sk > myq) ? -1e30f : v;
                        sacc[t][g * 4 + r2] = v;
                        mx = fmaxf(mx, v);
                    }
                }
        }

        // online softmax (exp2 domain): 32 in-lane + 1 cross-half shuffle
        mx = fmaxf(mx, __shfl_xor(mx, 32, 64));
        float mnew  = fmaxf(m_s, mx);
        float alpha = exp2f(m_s - mnew);
        float rs = 0.0f;
#pragma unroll
        for (int t = 0; t < 2; t++)
#pragma unroll
            for (int c = 0; c < 16; c++) {
                float p = exp2f(sacc[t][c] - mnew);
                sacc[t][c] = p;
                rs += p;
            }
        l_s = l_s * alpha + rs;
        m_s = mnew;
#pragma unroll
        for (int dt = 0; dt < 4; dt++) oacc[dt] *= alpha;

        // PV: build P B-fragments in-register via cross-half exchange.
        // C reg r holds key (r&3)+8*(r>>2)+4*half (+32t); dword i=r>>1.
#pragma unroll
        for (int t = 0; t < 2; t++) {
            unsigned w8[8];
#pragma unroll
            for (int i = 0; i < 8; i++)
                w8[i] = pack2(sacc[t][2 * i], sacc[t][2 * i + 1]);
#pragma unroll
            for (int s2 = 0; s2 < 2; s2++) {
                const int bse = 4 * s2;
                unsigned a0 = half ? w8[bse]     : w8[bse + 2];
                unsigned a1 = half ? w8[bse + 1] : w8[bse + 3];
                unsigned z0 = (unsigned)__shfl_xor((int)a0, 32, 64);
                unsigned z1 = (unsigned)__shfl_xor((int)a1, 32, 64);
                union { unsigned u[4]; bf16x8 v; } pu;
                pu.u[0] = half ? z0 : w8[bse];
                pu.u[1] = half ? z1 : w8[bse + 1];
                pu.u[2] = half ? w8[bse + 2] : z0;
                pu.u[3] = half ? w8[bse + 3] : z1;
                bf16x8 pf = pu.v;
                const int c = (t * 2 + s2) * 2 + half;   // key-chunk for vf
#pragma unroll
                for (int dt = 0; dt < 4; dt++) {
                    int row = dt * 32 + l31;
                    int x = c ^ swv;
                    bf16x8 vf = *(const bf16x8*)(sVb + row * 64 + x * 8);
                    oacc[dt] = MFMA32(vf, pf, oacc[dt]);
                }
            }
        }
        // single barrier/iter: drains prefetch (landed during compute) and
        // retires all reads of the current buffer before it is overwritten.
        __syncthreads();
    }

    // merge per-half l, store O^T -> [b, s, h*128+d]
    l_s += __shfl_xor(l_s, 32, 64);
    float inv = 1.0f / l_s;
    size_t base = ((size_t)(b * 2048 + myq)) * 2048 + hh * 128;
#pragma unroll
    for (int dt = 0; dt < 4; dt++)
#pragma unroll
        for (int g = 0; g < 4; g++) {
            bf16x4 o4;
#pragma unroll
            for (int r2 = 0; r2 < 4; r2++) o4[r2] = (bf16)(oacc[dt][g * 4 + r2] * inv);
            *(bf16x4*)(O + base + dt * 32 + 8 * g + 4 * half) = o4;
        }
}

extern "C" void kernel_launch(void* const* d_in, const int* in_sizes, int n_in,
                              void* d_out, int out_size, void* d_ws, size_t ws_size,
                              hipStream_t stream) {
    const float* x     = (const float*)d_in[0];
    const int*   am    = (const int*)d_in[1];
    const float* qkvw  = (const float*)d_in[2];
    const float* qkvb  = (const float*)d_in[3];
    const float* outw  = (const float*)d_in[4];
    const float* outb  = (const float*)d_in[5];
    float* out = (float*)d_out;

    char* ws = (char*)d_ws;
    bf16*  xb    = (bf16*)(ws);                          // 16 MB  x bf16 [4096,2048]
    bf16*  wqkv  = (bf16*)(ws + (16ull << 20));          // 24 MB  qkv_w bf16 [6144,2048]
    bf16*  wout  = (bf16*)(ws + (40ull << 20));          //  8 MB  out_w bf16 [2048,2048]
    bf16*  qb    = (bf16*)(ws + (48ull << 20));          // 16 MB  q (pre-scaled /ln2)
    bf16*  kb    = (bf16*)(ws + (64ull << 20));          // 16 MB  k
    bf16*  vtb   = (bf16*)(ws + (80ull << 20));          // 16 MB  v^T [32, 128, 2048]
    bf16*  attn  = (bf16*)(ws + (96ull << 20));          // 16 MB  attn [4096, 2048]
    float* cosT  = (float*)(ws + (112ull << 20));        //  1 MB
    float* sinT  = (float*)(ws + (113ull << 20));        //  1 MB
    float* mbias = (float*)(ws + (114ull << 20));        // 16 KB

    cvt8<<<4096, 256, 0, stream>>>(x, xb, 4096 * 2048);
    cvt8<<<6144, 256, 0, stream>>>(qkvw, wqkv, 6144 * 2048);
    cvt8<<<2048, 256, 0, stream>>>(outw, wout, 2048 * 2048);
    tables_k<<<1024, 256, 0, stream>>>(am, cosT, sinT, mbias);

    gemm_bt<1><<<dim3(32, 24), 256, 0, stream>>>(
        xb, wqkv, qkvb, nullptr, qb, kb, vtb, cosT, sinT, 4096, 6144, 2048, 0);
    gemm_bt<1><<<dim3(32, 24), 256, 0, stream>>>(
        xb, wqkv, qkvb, nullptr, qb, kb, vtb, cosT, sinT, 4096, 6144, 2048, 24);

    fattn<<<dim3(512), 256, 0, stream>>>(qb, kb, vtb, mbias, attn);

    gemm_bt<0><<<dim3(32, 16), 256, 0, stream>>>(
        attn, wout, outb, out, nullptr, nullptr, nullptr, nullptr, nullptr,
        4096, 2048, 2048, 0);
}

// Round 7
// 385.644 us; speedup vs baseline: 1.0628x; 1.0628x over previous
//
#include <hip/hip_runtime.h>

typedef __bf16 bf16;
typedef __bf16 bf16x2 __attribute__((ext_vector_type(2)));
typedef __bf16 bf16x4 __attribute__((ext_vector_type(4)));
typedef __bf16 bf16x8 __attribute__((ext_vector_type(8)));
typedef float f32x4 __attribute__((ext_vector_type(4)));
typedef float f32x16 __attribute__((ext_vector_type(16)));

#define MFMA_BF16(a, b, c) __builtin_amdgcn_mfma_f32_16x16x32_bf16(a, b, c, 0, 0, 0)
#define MFMA32(a, b, c)    __builtin_amdgcn_mfma_f32_32x32x16_bf16(a, b, c, 0, 0, 0)

__device__ __forceinline__ void async16(const void* g, void* l) {
    __builtin_amdgcn_global_load_lds(
        (const __attribute__((address_space(1))) void*)g,
        (__attribute__((address_space(3))) void*)l,
        16, 0, 0);
}

__device__ __forceinline__ unsigned pack2(float a, float b) {
    bf16x2 t; t[0] = (bf16)a; t[1] = (bf16)b;
    return __builtin_bit_cast(unsigned, t);
}

// ---------------- prep: all fp32->bf16 converts + RoPE tables + mask, ONE dispatch ----------------
__device__ __forceinline__ void cvt8_body(const float* __restrict__ in,
                                          bf16* __restrict__ out, int blk) {
    int i = (blk * 256 + (int)threadIdx.x) * 8;
    float4 a = *(const float4*)(in + i);
    float4 b = *(const float4*)(in + i + 4);
    bf16x8 o;
    o[0] = (bf16)a.x; o[1] = (bf16)a.y; o[2] = (bf16)a.z; o[3] = (bf16)a.w;
    o[4] = (bf16)b.x; o[5] = (bf16)b.y; o[6] = (bf16)b.z; o[7] = (bf16)b.w;
    *(bf16x8*)(out + i) = o;
}

__global__ void prep(const float* __restrict__ x, const float* __restrict__ qkvw,
                     const float* __restrict__ outw, const int* __restrict__ am,
                     bf16* __restrict__ xb, bf16* __restrict__ wqkv, bf16* __restrict__ wout,
                     float* __restrict__ cosT, float* __restrict__ sinT,
                     float* __restrict__ mbias) {
    int blk = blockIdx.x;
    if (blk < 4096)        cvt8_body(x,    xb,   blk);
    else if (blk < 10240)  cvt8_body(qkvw, wqkv, blk - 4096);
    else if (blk < 12288)  cvt8_body(outw, wout, blk - 10240);
    else {
        int i = (blk - 12288) * 256 + threadIdx.x;   // 0 .. 2048*128-1
        int s = i >> 7, d = i & 127, fi = d & 63;
        float inv = exp2f(-(float)fi * (13.287712379549449f / 64.0f));
        float ang = (float)s * inv;
        cosT[i] = cosf(ang);
        sinT[i] = sinf(ang);
        if (i < 2 * 2048) mbias[i] = (am[i] == 0) ? -1.4427e30f : 0.0f;  // exp2 domain
    }
}

// ---------------- GEMM: C[M,N] = A[M,K] @ Bt[N,K]^T + bias ----------------
// (m97-structure plateau, ~830 TF; unchanged logic)
template <int EPI>
__global__ void __launch_bounds__(256, 2)
gemm_bt(const bf16* __restrict__ A, const bf16* __restrict__ Bt,
        const float* __restrict__ bias, float* __restrict__ Cf,
        bf16* __restrict__ qb, bf16* __restrict__ kb, bf16* __restrict__ vtb,
        const float* __restrict__ cosT, const float* __restrict__ sinT,
        int M, int N, int K) {
    __shared__ __align__(16) bf16 sA[128 * 64];
    __shared__ __align__(16) bf16 sB[128 * 64];
    const int tid  = threadIdx.x;
    const int lane = tid & 63;
    const int quad = lane >> 4, l15 = lane & 15;
    const int wid = tid >> 6, wm = wid >> 1, wn = wid & 1;
    const int bm = blockIdx.x, bn = blockIdx.y;

    f32x4 acc[4][4];
#pragma unroll
    for (int i = 0; i < 4; i++)
#pragma unroll
        for (int j = 0; j < 4; j++)
#pragma unroll
            for (int c = 0; c < 4; c++) acc[i][j][c] = 0.0f;

    const int r0 = tid >> 3, x0 = tid & 7;
    const int g0 = x0 ^ (r0 & 7);
    const bf16* pa = A  + (size_t)(bm * 128 + r0) * K + g0 * 8;
    const bf16* pb = Bt + (size_t)(bn * 128 + r0) * K + g0 * 8;
    bf16* la = sA + tid * 8;
    bf16* lb = sB + tid * 8;
    const size_t gstep = (size_t)32 * K;

    for (int k0 = 0; k0 < K; k0 += 64) {
#pragma unroll
        for (int i = 0; i < 4; i++) {
            async16(pa + i * gstep, la + i * 2048);
            async16(pb + i * gstep, lb + i * 2048);
        }
        pa += 64; pb += 64;
        __syncthreads();
#pragma unroll
        for (int ks = 0; ks < 2; ks++) {
            bf16x8 af[4], bfr[4];
#pragma unroll
            for (int i = 0; i < 4; i++) {
                int r = wm * 64 + i * 16 + l15;
                int x = (ks * 4 + quad) ^ (r & 7);
                af[i] = *(const bf16x8*)(sA + r * 64 + x * 8);
            }
#pragma unroll
            for (int i = 0; i < 4; i++) {
                int r = wn * 64 + i * 16 + l15;
                int x = (ks * 4 + quad) ^ (r & 7);
                bfr[i] = *(const bf16x8*)(sB + r * 64 + x * 8);
            }
#pragma unroll
            for (int mi = 0; mi < 4; mi++)
#pragma unroll
                for (int ni = 0; ni < 4; ni++)
                    acc[mi][ni] = MFMA_BF16(af[mi], bfr[ni], acc[mi][ni]);
        }
        __syncthreads();
    }

    if (EPI == 0) {
#pragma unroll
        for (int mi = 0; mi < 4; mi++)
#pragma unroll
            for (int ni = 0; ni < 4; ni++) {
                int row0 = bm * 128 + wm * 64 + mi * 16 + quad * 4;
                int col  = bn * 128 + wn * 64 + ni * 16 + l15;
                float bv = bias[col];
#pragma unroll
                for (int r = 0; r < 4; r++)
                    Cf[(size_t)(row0 + r) * N + col] = acc[mi][ni][r] + bv;
            }
    } else {
#pragma unroll
        for (int mi = 0; mi < 4; mi++)
#pragma unroll
            for (int ni = 0; ni < 4; ni++) {
                int col   = bn * 128 + wn * 64 + ni * 16 + l15;
                int which = col >> 11;
                int hcol  = col & 2047;
                int h = hcol >> 7, d = hcol & 127;
                float bv = bias[col];
#pragma unroll
                for (int r = 0; r < 4; r++) {
                    int row = bm * 128 + wm * 64 + mi * 16 + quad * 4 + r;
                    int b = row >> 11, s = row & 2047;
                    float v  = acc[mi][ni][r] + bv;
                    float vp = __shfl_xor(v, 1, 64);   // partner column d^1
                    float ov = v;
                    if (which < 2) {
                        float c  = cosT[(s << 7) + d];
                        float sn = sinT[(s << 7) + d];
                        ov = v * c + ((d & 1) ? vp : -vp) * sn;
                    }
                    // q pre-scale: 1/sqrt(128)/ln2 (exp2-domain softmax)
                    if (which == 0) ov *= 0.12751743f;
                    size_t bh = (size_t)(b * 16 + h);
                    if (which == 0)      qb[(bh * 2048 + s) * 128 + d] = (bf16)ov;
                    else if (which == 1) kb[(bh * 2048 + s) * 128 + d] = (bf16)ov;
                    else                 vtb[(bh * 128 + d) * 2048 + s] = (bf16)ov;
                }
            }
    }
}

// ---------------- Flash attention v6: uniform split-K, 17 tiles/block ----------------
// Grid 512 1-D: id -> bh = id&31, v = id>>5, p = v>>1, role = v&1.
// Pair (heavy qt a=15-p [nkt=32-2p], light qt p [nkt=2p+2]); 34 tiles split:
//   role 0: qt=a, tiles [0,17)            -> partial slot (bh,a,0)
//   role 1: qt=a, tiles [17,32-2p)        -> partial slot (bh,a,1)
//           then qt=p, tiles [0,2p+2)     -> direct write (normalized)
// Partials: unnormalized O^T (fp32) + (m,l) per q-row; merged by combine().
__global__ void __launch_bounds__(256, 2)
fattn(const bf16* __restrict__ Q, const bf16* __restrict__ Kg,
      const bf16* __restrict__ Vt, const float* __restrict__ mbias,
      bf16* __restrict__ O, float* __restrict__ Opart, float* __restrict__ mlpart) {
    __shared__ __align__(16) bf16 sK[2][64 * 128];   // [buf][key][d]
    __shared__ __align__(16) bf16 sV[2][128 * 64];   // [buf][d][key]
    const int tid = threadIdx.x, lane = tid & 63, w = tid >> 6;
    const int l31 = lane & 31, half = lane >> 5;
    const int id = (int)blockIdx.x;
    const int bh = id & 31, v = id >> 5;
    const int p = v >> 1, role = v & 1;
    const int qa = 15 - p;                 // heavy q-tile
    const int n1 = role ? (15 - 2 * p) : 17;   // first-segment tile count

    const bf16* Qb  = Q  + (size_t)bh * 2048 * 128;
    const bf16* Kbh = Kg + (size_t)bh * 2048 * 128;
    const bf16* Vbh = Vt + (size_t)bh * 128 * 2048;
    const int b = bh >> 4, hh = bh & 15;
    const float* mbb = mbias + b * 2048;

    // per-lane read swizzles (full-bank coverage)
    const int swk = (l31 & 15) ^ (l31 >> 4);
    const int swv = (l31 & 7) ^ ((l31 >> 3) & 3);
    // staging indices
    const int rk = tid >> 4, xk = tid & 15, gkb = xk ^ rk;   // ^ (i&1) per i
    const int rv = tid >> 3, xv = tid & 7;
    const int gv = xv ^ (rv & 7) ^ ((rv >> 3) & 3);

    // tile t in [0,17) -> key-tile index
    auto KT = [&](int t) { return role ? (t < n1 ? 17 + t : t - n1) : t; };

    int qt = qa;
    int myq  = qt * 128 + w * 32 + l31;
    int qmin = qt * 128 + w * 32;

    bf16x8 qf[8];
#pragma unroll
    for (int kq = 0; kq < 8; kq++)
        qf[kq] = *(const bf16x8*)(Qb + (size_t)myq * 128 + kq * 16 + half * 8);

    f32x16 oacc[4];
#pragma unroll
    for (int dt = 0; dt < 4; dt++)
#pragma unroll
        for (int c = 0; c < 16; c++) oacc[dt][c] = 0.0f;
    float m_s = -3e38f, l_s = 0.0f;

    // stage tile 0 into buffer 0
    {
        int kb0 = KT(0) * 64;
#pragma unroll
        for (int i = 0; i < 4; i++) {
            async16(Kbh + (size_t)(kb0 + rk + i * 16) * 128 + (gkb ^ (i & 1)) * 8,
                    &sK[0][(i * 256 + tid) * 8]);
            async16(Vbh + (size_t)(rv + i * 32) * 2048 + kb0 + gv * 8,
                    &sV[0][(i * 256 + tid) * 8]);
        }
    }
    __syncthreads();

    for (int t = 0; t < 17; t++) {
        // segment boundary (role 1 only): finalize heavy partial, switch to light qt
        if (role && t == n1) {
            float lf = l_s + __shfl_xor(l_s, 32, 64);
            size_t slot = (size_t)(bh * 8 + (qa - 8)) * 2 + 1;
            float* op = Opart + slot * 16384 + (size_t)(w * 32 + l31) * 128;
#pragma unroll
            for (int dt = 0; dt < 4; dt++)
#pragma unroll
                for (int g = 0; g < 4; g++) {
                    float4 o4 = make_float4(oacc[dt][g * 4 + 0], oacc[dt][g * 4 + 1],
                                            oacc[dt][g * 4 + 2], oacc[dt][g * 4 + 3]);
                    *(float4*)(op + dt * 32 + 8 * g + 4 * half) = o4;
                }
            if (half == 0) {
                float* mp = mlpart + (slot * 128 + (w * 32 + l31)) * 2;
                mp[0] = m_s; mp[1] = lf;
            }
#pragma unroll
            for (int dt = 0; dt < 4; dt++)
#pragma unroll
                for (int c = 0; c < 16; c++) oacc[dt][c] = 0.0f;
            m_s = -3e38f; l_s = 0.0f;
            qt = p;   // light q-tile
            myq  = qt * 128 + w * 32 + l31;
            qmin = qt * 128 + w * 32;
#pragma unroll
            for (int kq = 0; kq < 8; kq++)
                qf[kq] = *(const bf16x8*)(Qb + (size_t)myq * 128 + kq * 16 + half * 8);
        }

        const int kb0 = KT(t) * 64;
        const int buf = t & 1;
        if (t + 1 < 17) {
            const int nb0 = KT(t + 1) * 64;
#pragma unroll
            for (int i = 0; i < 4; i++) {
                async16(Kbh + (size_t)(nb0 + rk + i * 16) * 128 + (gkb ^ (i & 1)) * 8,
                        &sK[buf ^ 1][(i * 256 + tid) * 8]);
                async16(Vbh + (size_t)(rv + i * 32) * 2048 + nb0 + gv * 8,
                        &sV[buf ^ 1][(i * 256 + tid) * 8]);
            }
        }
        const bf16* sKb = sK[buf];
        const bf16* sVb = sV[buf];

        // S^T: rows = keys (2 tiles of 32), col = query
        f32x16 sacc[2];
#pragma unroll
        for (int tt = 0; tt < 2; tt++)
#pragma unroll
            for (int c = 0; c < 16; c++) sacc[tt][c] = 0.0f;
#pragma unroll
        for (int kq = 0; kq < 8; kq++) {
#pragma unroll
            for (int tt = 0; tt < 2; tt++) {
                int row = tt * 32 + l31;
                int x = (kq * 2 + half) ^ swk;
                bf16x8 kf = *(const bf16x8*)(sKb + row * 128 + x * 8);
                sacc[tt] = MFMA32(kf, qf[kq], sacc[tt]);
            }
        }

        // mask in-place (exp2 domain)
        float mx = -3e38f;
        if (kb0 + 63 < qmin) {          // interior tile
#pragma unroll
            for (int tt = 0; tt < 2; tt++)
#pragma unroll
                for (int g = 0; g < 4; g++) {
                    float4 mb4 = *(const float4*)(mbb + kb0 + tt * 32 + 8 * g + 4 * half);
#pragma unroll
                    for (int r2 = 0; r2 < 4; r2++) {
                        float vv = sacc[tt][g * 4 + r2] + ((const float*)&mb4)[r2];
                        sacc[tt][g * 4 + r2] = vv;
                        mx = fmaxf(mx, vv);
                    }
                }
        } else {
#pragma unroll
            for (int tt = 0; tt < 2; tt++)
#pragma unroll
                for (int g = 0; g < 4; g++) {
                    float4 mb4 = *(const float4*)(mbb + kb0 + tt * 32 + 8 * g + 4 * half);
#pragma unroll
                    for (int r2 = 0; r2 < 4; r2++) {
                        int sk = kb0 + tt * 32 + 8 * g + 4 * half + r2;
                        float vv = sacc[tt][g * 4 + r2] + ((const float*)&mb4)[r2];
                        vv = (sk > myq) ? -1e30f : vv;
                        sacc[tt][g * 4 + r2] = vv;
                        mx = fmaxf(mx, vv);
                    }
                }
        }

        // online softmax (exp2 domain): 32 in-lane + 1 cross-half shuffle
        mx = fmaxf(mx, __shfl_xor(mx, 32, 64));
        float mnew  = fmaxf(m_s, mx);
        float alpha = exp2f(m_s - mnew);
        float rs = 0.0f;
#pragma unroll
        for (int tt = 0; tt < 2; tt++)
#pragma unroll
            for (int c = 0; c < 16; c++) {
                float pe = exp2f(sacc[tt][c] - mnew);
                sacc[tt][c] = pe;
                rs += pe;
            }
        l_s = l_s * alpha + rs;
        m_s = mnew;
#pragma unroll
        for (int dt = 0; dt < 4; dt++) oacc[dt] *= alpha;

        // PV: P B-fragments in-register via cross-half dword exchange
#pragma unroll
        for (int tt = 0; tt < 2; tt++) {
            unsigned w8[8];
#pragma unroll
            for (int i = 0; i < 8; i++)
                w8[i] = pack2(sacc[tt][2 * i], sacc[tt][2 * i + 1]);
#pragma unroll
            for (int s2 = 0; s2 < 2; s2++) {
                const int bse = 4 * s2;
                unsigned a0 = half ? w8[bse]     : w8[bse + 2];
                unsigned a1 = half ? w8[bse + 1] : w8[bse + 3];
                unsigned z0 = (unsigned)__shfl_xor((int)a0, 32, 64);
                unsigned z1 = (unsigned)__shfl_xor((int)a1, 32, 64);
                union { unsigned u[4]; bf16x8 vv; } pu;
                pu.u[0] = half ? z0 : w8[bse];
                pu.u[1] = half ? z1 : w8[bse + 1];
                pu.u[2] = half ? w8[bse + 2] : z0;
                pu.u[3] = half ? w8[bse + 3] : z1;
                bf16x8 pf = pu.vv;
                const int c = (tt * 2 + s2) * 2 + half;
#pragma unroll
                for (int dt = 0; dt < 4; dt++) {
                    int row = dt * 32 + l31;
                    int x = c ^ swv;
                    bf16x8 vf = *(const bf16x8*)(sVb + row * 64 + x * 8);
                    oacc[dt] = MFMA32(vf, pf, oacc[dt]);
                }
            }
        }
        __syncthreads();
    }

    // epilogue
    float lf = l_s + __shfl_xor(l_s, 32, 64);
    if (role == 0) {
        size_t slot = (size_t)(bh * 8 + (qa - 8)) * 2 + 0;
        float* op = Opart + slot * 16384 + (size_t)(w * 32 + l31) * 128;
#pragma unroll
        for (int dt = 0; dt < 4; dt++)
#pragma unroll
            for (int g = 0; g < 4; g++) {
                float4 o4 = make_float4(oacc[dt][g * 4 + 0], oacc[dt][g * 4 + 1],
                                        oacc[dt][g * 4 + 2], oacc[dt][g * 4 + 3]);
                *(float4*)(op + dt * 32 + 8 * g + 4 * half) = o4;
            }
        if (half == 0) {
            float* mp = mlpart + (slot * 128 + (w * 32 + l31)) * 2;
            mp[0] = m_s; mp[1] = lf;
        }
    } else {
        float inv = 1.0f / lf;
        size_t base = ((size_t)(b * 2048 + myq)) * 2048 + hh * 128;
#pragma unroll
        for (int dt = 0; dt < 4; dt++)
#pragma unroll
            for (int g = 0; g < 4; g++) {
                bf16x4 o4;
#pragma unroll
                for (int r2 = 0; r2 < 4; r2++) o4[r2] = (bf16)(oacc[dt][g * 4 + r2] * inv);
                *(bf16x4*)(O + base + dt * 32 + 8 * g + 4 * half) = o4;
            }
    }
}

// ---------------- combine: merge split-K partials for heavy q-tiles ----------------
__global__ void combine(const float* __restrict__ Opart, const float* __restrict__ mlpart,
                        bf16* __restrict__ attn) {
    int i = blockIdx.x * 256 + threadIdx.x;     // 1,048,576 quads
    int dq = (i & 31) * 4;
    int row = i >> 5;                            // (bh*8+ai)*128 + qloc
    int qloc = row & 127, ba = row >> 7;
    int ai = ba & 7, bh = ba >> 3;
    const float* mlA = mlpart + ((size_t)(ba * 2 + 0) * 128 + qloc) * 2;
    const float* mlB = mlpart + ((size_t)(ba * 2 + 1) * 128 + qloc) * 2;
    float mA = mlA[0], lA = mlA[1], mB = mlB[0], lB = mlB[1];
    float m = fmaxf(mA, mB);
    float wA = exp2f(mA - m), wB = exp2f(mB - m);
    float inv = 1.0f / (wA * lA + wB * lB);
    float4 oA = *(const float4*)(Opart + (size_t)(ba * 2 + 0) * 16384 + qloc * 128 + dq);
    float4 oB = *(const float4*)(Opart + (size_t)(ba * 2 + 1) * 16384 + qloc * 128 + dq);
    int q = (8 + ai) * 128 + qloc;
    int b = bh >> 4, hh = bh & 15;
    bf16x4 o4;
    o4[0] = (bf16)((wA * oA.x + wB * oB.x) * inv);
    o4[1] = (bf16)((wA * oA.y + wB * oB.y) * inv);
    o4[2] = (bf16)((wA * oA.z + wB * oB.z) * inv);
    o4[3] = (bf16)((wA * oA.w + wB * oB.w) * inv);
    *(bf16x4*)(attn + ((size_t)(b * 2048 + q)) * 2048 + hh * 128 + dq) = o4;
}

extern "C" void kernel_launch(void* const* d_in, const int* in_sizes, int n_in,
                              void* d_out, int out_size, void* d_ws, size_t ws_size,
                              hipStream_t stream) {
    const float* x     = (const float*)d_in[0];
    const int*   am    = (const int*)d_in[1];
    const float* qkvw  = (const float*)d_in[2];
    const float* qkvb  = (const float*)d_in[3];
    const float* outw  = (const float*)d_in[4];
    const float* outb  = (const float*)d_in[5];
    float* out = (float*)d_out;

    char* ws = (char*)d_ws;
    bf16*  xb    = (bf16*)(ws);                          // 16 MB  x bf16
    bf16*  wqkv  = (bf16*)(ws + (16ull << 20));          // 24 MB  qkv_w bf16
    bf16*  wout  = (bf16*)(ws + (40ull << 20));          //  8 MB  out_w bf16
    bf16*  qb    = (bf16*)(ws + (48ull << 20));          // 16 MB  q (pre-scaled /ln2)
    bf16*  kb    = (bf16*)(ws + (64ull << 20));          // 16 MB  k
    bf16*  vtb   = (bf16*)(ws + (80ull << 20));          // 16 MB  v^T
    bf16*  attn  = (bf16*)(ws + (96ull << 20));          // 16 MB  attn [4096,2048]
    float* cosT  = (float*)(ws + (112ull << 20));        //  1 MB
    float* sinT  = (float*)(ws + (113ull << 20));        //  1 MB
    float* mbias = (float*)(ws + (114ull << 20));        // 16 KB
    // split-K partials ALIAS xb/wqkv (dead after gemm1; stream order guarantees safety)
    float* Opart  = (float*)(ws);                        // 32 MB  [32bh][8a][2role][128q][128d]
    float* mlpart = (float*)(ws + (32ull << 20));        // 0.5 MB [.][.][.][128q][m,l]

    prep<<<13312, 256, 0, stream>>>(x, qkvw, outw, am, xb, wqkv, wout, cosT, sinT, mbias);

    gemm_bt<1><<<dim3(32, 48), 256, 0, stream>>>(
        xb, wqkv, qkvb, nullptr, qb, kb, vtb, cosT, sinT, 4096, 6144, 2048);

    fattn<<<dim3(512), 256, 0, stream>>>(qb, kb, vtb, mbias, attn, Opart, mlpart);

    combine<<<4096, 256, 0, stream>>>(Opart, mlpart, attn);

    gemm_bt<0><<<dim3(32, 16), 256, 0, stream>>>(
        attn, wout, outb, out, nullptr, nullptr, nullptr, nullptr, nullptr,
        4096, 2048, 2048);
}